// Round 15
// baseline (927.907 us; speedup 1.0000x reference)
//
#include <hip/hip_runtime.h>
#include <hip/hip_bf16.h>

#define B_TOT 65536
#define WPT_FLOATS (64 * 32 * 128)  // 262144 floats = 1 MiB

// Round-15: R14 + S5 address-stream surgery in udp_dist:
//  - pp = t>>6 hoisted via readfirstlane -> the four WpT base addresses
//    become SGPR-resident (wave-uniform); loads share one VGPR offset.
//  - ff loop unrolled x4 -> WpT loads use imm offsets 0/1024/2048/3072
//    (13-bit signed range) and fv ds_reads use imm offsets r*512+u*16;
//    one address bump per 4 iterations instead of 12 v_adds/iter.
//  Frees ~8 VGPRs under the 84 cap and cuts non-FMA VALU ~30%.
// No arithmetic change anywhere -> bit-exact vs baseline.

// ---------------- Kernel A: MLP (+ WpT staging prologue) ----------------
__global__ __launch_bounds__(256, 2) void udp_mlp(
    const float* __restrict__ obs, const float* __restrict__ act,
    const float* __restrict__ obs2, const float* __restrict__ rew,
    const float* __restrict__ W0, const float* __restrict__ b0,
    const float* __restrict__ W1, const float* __restrict__ b1,
    const float* __restrict__ W2, const float* __restrict__ b2,
    const float* __restrict__ Wp, float* __restrict__ WpT,
    float* __restrict__ out) {
  __shared__ __align__(16) float A_[5120];   // xs[32][160] 20KB
  __shared__ __align__(16) float Bb[8192];   // h1->h2 [32][256] 32KB
  const int t = threadIdx.x;
  const int blockRow = blockIdx.x * 32;

  float* out0 = out;                        // feat[:,0:32) stash
  float* out3 = out + (size_t)B_TOT * 34;   // feat[:,32:64) stash
  float* out4 = out + (size_t)B_TOT * 66;   // feat[:,64:128) stash

  // ---- S0: WpT staging slice (128 elems/block; 2048*128 = 262144) ----
  // WpT[idx], idx = e*8192 + f4*256 + n*4 + j <- Wp[(n*32+e)*128 + f4*4 + j]
  if (WpT != nullptr && t < 128) {
    const int idx = blockIdx.x * 128 + t;
    const int j  = idx & 3;
    const int n  = (idx >> 2) & 63;
    const int f4 = (idx >> 8) & 31;
    const int e  = idx >> 13;
    WpT[idx] = Wp[(n * 32 + e) * 128 + f4 * 4 + j];
  }

  // ---- S1: stage x = [obs | obs2-obs | act | rew] into A_ ----
  for (int i = t; i < 32 * 160; i += 256) {
    int r = i / 160, k = i - r * 160;
    int row = blockRow + r;
    float v;
    if (k < 64)        v = obs[row * 64 + k];
    else if (k < 128)  v = obs2[row * 64 + (k - 64)] - obs[row * 64 + (k - 64)];
    else if (k < 144)  v = act[row * 16 + (k - 128)];
    else if (k == 144) v = rew[row];
    else               v = 0.f;
    A_[i] = v;
  }
  __syncthreads();

  // ---- S2: layer 0 (145 -> 256). 4 neurons x 8 rows per thread ----
  {
    const int n4 = (t & 63) * 4;
    const int rbase = (t >> 6) * 8;  // wave-uniform
    float aA[8], aB[8], aC[8], aD[8];
#pragma unroll
    for (int r = 0; r < 8; ++r) { aA[r] = 0.f; aB[r] = 0.f; aC[r] = 0.f; aD[r] = 0.f; }
    const float4 bb = *(const float4*)&b0[n4];
    const float4 wt = *(const float4*)&W0[144 * 256 + n4];
    for (int k4 = 0; k4 < 144; k4 += 4) {
      const float4 w0 = *(const float4*)&W0[(k4 + 0) * 256 + n4];
      const float4 w1 = *(const float4*)&W0[(k4 + 1) * 256 + n4];
      const float4 w2 = *(const float4*)&W0[(k4 + 2) * 256 + n4];
      const float4 w3 = *(const float4*)&W0[(k4 + 3) * 256 + n4];
#pragma unroll
      for (int r = 0; r < 8; ++r) {
        const float4 xv = *(const float4*)&A_[(rbase + r) * 160 + k4];  // broadcast
        aA[r] = fmaf(xv.x, w0.x, aA[r]); aA[r] = fmaf(xv.y, w1.x, aA[r]);
        aA[r] = fmaf(xv.z, w2.x, aA[r]); aA[r] = fmaf(xv.w, w3.x, aA[r]);
        aB[r] = fmaf(xv.x, w0.y, aB[r]); aB[r] = fmaf(xv.y, w1.y, aB[r]);
        aB[r] = fmaf(xv.z, w2.y, aB[r]); aB[r] = fmaf(xv.w, w3.y, aB[r]);
        aC[r] = fmaf(xv.x, w0.z, aC[r]); aC[r] = fmaf(xv.y, w1.z, aC[r]);
        aC[r] = fmaf(xv.z, w2.z, aC[r]); aC[r] = fmaf(xv.w, w3.z, aC[r]);
        aD[r] = fmaf(xv.x, w0.w, aD[r]); aD[r] = fmaf(xv.y, w1.w, aD[r]);
        aD[r] = fmaf(xv.z, w2.w, aD[r]); aD[r] = fmaf(xv.w, w3.w, aD[r]);
      }
    }
#pragma unroll
    for (int r = 0; r < 8; ++r) {
      const float xt = A_[(rbase + r) * 160 + 144];
      aA[r] = fmaf(xt, wt.x, aA[r]); aB[r] = fmaf(xt, wt.y, aB[r]);
      aC[r] = fmaf(xt, wt.z, aC[r]); aD[r] = fmaf(xt, wt.w, aD[r]);
    }
#pragma unroll
    for (int r = 0; r < 8; ++r) {
      float4 v;
      v.x = aA[r] + bb.x; v.x = v.x > 0.f ? v.x : 0.01f * v.x;
      v.y = aB[r] + bb.y; v.y = v.y > 0.f ? v.y : 0.01f * v.y;
      v.z = aC[r] + bb.z; v.z = v.z > 0.f ? v.z : 0.01f * v.z;
      v.w = aD[r] + bb.w; v.w = v.w > 0.f ? v.w : 0.01f * v.w;
      *(float4*)&Bb[(rbase + r) * 256 + n4] = v;  // h1
    }
  }
  __syncthreads();

  // ---- S3: layer 1 (256 -> 256). h2 overwrites h1 (barrier before write) ----
  {
    const int n4 = (t & 63) * 4;
    const int rbase = (t >> 6) * 8;
    float aA[8], aB[8], aC[8], aD[8];
#pragma unroll
    for (int r = 0; r < 8; ++r) { aA[r] = 0.f; aB[r] = 0.f; aC[r] = 0.f; aD[r] = 0.f; }
    const float4 bb = *(const float4*)&b1[n4];
    for (int k4 = 0; k4 < 256; k4 += 4) {
      const float4 w0 = *(const float4*)&W1[(k4 + 0) * 256 + n4];
      const float4 w1 = *(const float4*)&W1[(k4 + 1) * 256 + n4];
      const float4 w2 = *(const float4*)&W1[(k4 + 2) * 256 + n4];
      const float4 w3 = *(const float4*)&W1[(k4 + 3) * 256 + n4];
#pragma unroll
      for (int r = 0; r < 8; ++r) {
        const float4 xv = *(const float4*)&Bb[(rbase + r) * 256 + k4];  // broadcast
        aA[r] = fmaf(xv.x, w0.x, aA[r]); aA[r] = fmaf(xv.y, w1.x, aA[r]);
        aA[r] = fmaf(xv.z, w2.x, aA[r]); aA[r] = fmaf(xv.w, w3.x, aA[r]);
        aB[r] = fmaf(xv.x, w0.y, aB[r]); aB[r] = fmaf(xv.y, w1.y, aB[r]);
        aB[r] = fmaf(xv.z, w2.y, aB[r]); aB[r] = fmaf(xv.w, w3.y, aB[r]);
        aC[r] = fmaf(xv.x, w0.z, aC[r]); aC[r] = fmaf(xv.y, w1.z, aC[r]);
        aC[r] = fmaf(xv.z, w2.z, aC[r]); aC[r] = fmaf(xv.w, w3.z, aC[r]);
        aD[r] = fmaf(xv.x, w0.w, aD[r]); aD[r] = fmaf(xv.y, w1.w, aD[r]);
        aD[r] = fmaf(xv.z, w2.w, aD[r]); aD[r] = fmaf(xv.w, w3.w, aD[r]);
      }
    }
    __syncthreads();  // all h1 reads done before any h2 write
#pragma unroll
    for (int r = 0; r < 8; ++r) {
      float4 v;
      v.x = aA[r] + bb.x; v.x = v.x > 0.f ? v.x : 0.01f * v.x;
      v.y = aB[r] + bb.y; v.y = v.y > 0.f ? v.y : 0.01f * v.y;
      v.z = aC[r] + bb.z; v.z = v.z > 0.f ? v.z : 0.01f * v.z;
      v.w = aD[r] + bb.w; v.w = v.w > 0.f ? v.w : 0.01f * v.w;
      *(float4*)&Bb[(rbase + r) * 256 + n4] = v;  // h2 (in place)
    }
  }
  __syncthreads();

  // ---- S4: layer 2 (256 -> 128). 4 neurons x 4 rows; feat -> global stash ----
  {
    const int n4 = (t & 31) * 4;
    const int rbase = (t >> 5) * 4;
    float aA[4], aB[4], aC[4], aD[4];
#pragma unroll
    for (int r = 0; r < 4; ++r) { aA[r] = 0.f; aB[r] = 0.f; aC[r] = 0.f; aD[r] = 0.f; }
    const float4 bb = *(const float4*)&b2[n4];
    for (int k4 = 0; k4 < 256; k4 += 4) {
      const float4 w0 = *(const float4*)&W2[(k4 + 0) * 128 + n4];
      const float4 w1 = *(const float4*)&W2[(k4 + 1) * 128 + n4];
      const float4 w2 = *(const float4*)&W2[(k4 + 2) * 128 + n4];
      const float4 w3 = *(const float4*)&W2[(k4 + 3) * 128 + n4];
#pragma unroll
      for (int r = 0; r < 4; ++r) {
        const float4 xv = *(const float4*)&Bb[(rbase + r) * 256 + k4];
        aA[r] = fmaf(xv.x, w0.x, aA[r]); aA[r] = fmaf(xv.y, w1.x, aA[r]);
        aA[r] = fmaf(xv.z, w2.x, aA[r]); aA[r] = fmaf(xv.w, w3.x, aA[r]);
        aB[r] = fmaf(xv.x, w0.y, aB[r]); aB[r] = fmaf(xv.y, w1.y, aB[r]);
        aB[r] = fmaf(xv.z, w2.y, aB[r]); aB[r] = fmaf(xv.w, w3.y, aB[r]);
        aC[r] = fmaf(xv.x, w0.z, aC[r]); aC[r] = fmaf(xv.y, w1.z, aC[r]);
        aC[r] = fmaf(xv.z, w2.z, aC[r]); aC[r] = fmaf(xv.w, w3.z, aC[r]);
        aD[r] = fmaf(xv.x, w0.w, aD[r]); aD[r] = fmaf(xv.y, w1.w, aD[r]);
        aD[r] = fmaf(xv.z, w2.w, aD[r]); aD[r] = fmaf(xv.w, w3.w, aD[r]);
      }
    }
#pragma unroll
    for (int r = 0; r < 4; ++r) {
      float4 v;
      v.x = aA[r] + bb.x; v.x = v.x > 0.f ? v.x : 0.01f * v.x;
      v.y = aB[r] + bb.y; v.y = v.y > 0.f ? v.y : 0.01f * v.y;
      v.z = aC[r] + bb.z; v.z = v.z > 0.f ? v.z : 0.01f * v.z;
      v.w = aD[r] + bb.w; v.w = v.w > 0.f ? v.w : 0.01f * v.w;
      const size_t row = (size_t)blockRow + rbase + r;
      if (n4 < 32)      *(float4*)&out0[row * 32 + n4] = v;
      else if (n4 < 64) *(float4*)&out3[row * 32 + (n4 - 32)] = v;
      else              *(float4*)&out4[row * 64 + (n4 - 64)] = v;
    }
  }
}

// ---------------- Kernel B: projection + distance + outputs ----------------
// COAL=1: Wp loads from WpT (coalesced, lane-stride 16B, wave-uniform base).
// COAL=0: fallback direct-Wp when ws too small.
template <int COAL>
__global__ __launch_bounds__(256, 2) void udp_dist(
    const float* __restrict__ Wp, const float* __restrict__ WpT,
    const float* __restrict__ emb, const float* __restrict__ sigma,
    float* __restrict__ out) {
  __shared__ __align__(16) float A_[8192];   // psum[32][4][64] swizzled, 32KB
  __shared__ __align__(16) float Bb[4096];   // feat[32][128] 16KB
  __shared__ float idxArr[32];
  const int t = threadIdx.x;
  const int blockRow = blockIdx.x * 32;

  float* out0 = out;                        // chosen_embedding (B,32) [feat stash 0:32]
  float* out1 = out + (size_t)B_TOT * 32;   // chosen_dist (B,1)
  float* out2 = out + (size_t)B_TOT * 33;   // idx (B,1) as float
  float* out3 = out + (size_t)B_TOT * 34;   // chosen_mean (B,32) [feat stash 32:64]
  float* out4 = out + (size_t)B_TOT * 66;   // distance (B,64)  [feat stash 64:128]

  // ---- F1: load feat stash -> LDS ----
  for (int i = t; i < 1024; i += 256) {   // 1024 float4s = 32*128
    const int r = i >> 5, c4 = (i & 31) * 4;
    const size_t row = (size_t)blockRow + r;
    float4 v;
    if (c4 < 32)      v = *(const float4*)&out0[row * 32 + c4];
    else if (c4 < 64) v = *(const float4*)&out3[row * 32 + (c4 - 32)];
    else              v = *(const float4*)&out4[row * 64 + (c4 - 64)];
    *(float4*)&Bb[r * 128 + c4] = v;
  }
  __syncthreads();

  // ---- S5: projection + diff^2, 4 emb-dims per pass (m-pair) ----
  // thread = (env n = t&63, partial pp = t>>6 wave-uniform via
  // readfirstlane -> WpT bases in SGPRs, loads share one VGPR offset).
  // Per mm: e00=2pp+16mm (m=2mm), e01=e00+1, e10=e00+8 (m=2mm+1), e11=e00+9.
  // ff unrolled x4: WpT imm offsets 0/1024/2048/3072, fv imm offsets.
  // rj updates m-ascending; dots ff-ascending xyzw -> bit-exact.
  {
    const int n = t & 63;
    const int pp = __builtin_amdgcn_readfirstlane(t >> 6);  // wave-uniform
    const float* eb = emb + n * 32;
#pragma unroll 1
    for (int q = 0; q < 4; ++q) {
      const int rbase = q * 8;
      float rj0[8], rj1[8];
#pragma unroll
      for (int r = 0; r < 8; ++r) { rj0[r] = 0.f; rj1[r] = 0.f; }
#pragma unroll 1
      for (int mm = 0; mm < 2; ++mm) {
        const int e00 = 2 * pp + 16 * mm;  // m = 2mm (scalar)
        const int e01 = e00 + 1;
        const int e10 = e00 + 8;           // m = 2mm+1
        const int e11 = e00 + 9;
        const float *p00, *p01, *p10, *p11;
        if (COAL) {
          // scalar base (e*8192) + per-lane offset (n*4) + ff imm
          p00 = WpT + e00 * 8192 + n * 4;
          p01 = WpT + e01 * 8192 + n * 4;
          p10 = WpT + e10 * 8192 + n * 4;
          p11 = WpT + e11 * 8192 + n * 4;
        } else {
          p00 = Wp + ((size_t)n * 32 + e00) * 128;
          p01 = Wp + ((size_t)n * 32 + e01) * 128;
          p10 = Wp + ((size_t)n * 32 + e10) * 128;
          p11 = Wp + ((size_t)n * 32 + e11) * 128;
        }
        const int WSTR = COAL ? 256 : 4;
        float a00[8], a01[8], a10[8], a11[8];
#pragma unroll
        for (int r = 0; r < 8; ++r) { a00[r] = 0.f; a01[r] = 0.f; a10[r] = 0.f; a11[r] = 0.f; }
#pragma unroll 4
        for (int ff = 0; ff < 32; ++ff) {
          const float4 w00 = *(const float4*)(p00 + ff * WSTR);
          const float4 w01 = *(const float4*)(p01 + ff * WSTR);
          const float4 w10 = *(const float4*)(p10 + ff * WSTR);
          const float4 w11 = *(const float4*)(p11 + ff * WSTR);
#pragma unroll
          for (int r = 0; r < 8; ++r) {
            const float4 fv = *(const float4*)&Bb[(rbase + r) * 128 + ff * 4];  // broadcast
            a00[r] = fmaf(fv.x, w00.x, a00[r]);
            a00[r] = fmaf(fv.y, w00.y, a00[r]);
            a00[r] = fmaf(fv.z, w00.z, a00[r]);
            a00[r] = fmaf(fv.w, w00.w, a00[r]);
            a01[r] = fmaf(fv.x, w01.x, a01[r]);
            a01[r] = fmaf(fv.y, w01.y, a01[r]);
            a01[r] = fmaf(fv.z, w01.z, a01[r]);
            a01[r] = fmaf(fv.w, w01.w, a01[r]);
            a10[r] = fmaf(fv.x, w10.x, a10[r]);
            a10[r] = fmaf(fv.y, w10.y, a10[r]);
            a10[r] = fmaf(fv.z, w10.z, a10[r]);
            a10[r] = fmaf(fv.w, w10.w, a10[r]);
            a11[r] = fmaf(fv.x, w11.x, a11[r]);
            a11[r] = fmaf(fv.y, w11.y, a11[r]);
            a11[r] = fmaf(fv.z, w11.z, a11[r]);
            a11[r] = fmaf(fv.w, w11.w, a11[r]);
          }
        }
        const float em00 = eb[e00], em01 = eb[e01];
        const float em10 = eb[e10], em11 = eb[e11];
#pragma unroll
        for (int r = 0; r < 8; ++r) {
          // m-ascending per chain: m=2mm first, then m=2mm+1
          float d;
          d = a00[r] - em00; rj0[r] = fmaf(d, d, rj0[r]);
          d = a01[r] - em01; rj1[r] = fmaf(d, d, rj1[r]);
          d = a10[r] - em10; rj0[r] = fmaf(d, d, rj0[r]);
          d = a11[r] - em11; rj1[r] = fmaf(d, d, rj1[r]);
        }
      }
      // psum[r][pp][(n+gr)&63]: write 2-way (free), S6 read conflict-free
#pragma unroll
      for (int r = 0; r < 8; ++r) {
        const int gr = rbase + r;
        A_[gr * 256 + pp * 64 + ((n + gr) & 63)] = rj0[r] + rj1[r];
      }
    }
  }
  __syncthreads();

  // ---- S6: distance + argmin, parallel: thread (r = t>>3, k = t&7) ----
  // covers nn in [8k, 8k+8) ascending (thread-local first-min), then
  // 3-step shfl_xor (val,idx) reduce with smaller-index tie-break ==
  // np.argmin first-min exactly. dist values bit-identical.
  {
    const int r = t >> 3, k = t & 7;
    float best = 1e30f;
    int bi = 0;
    for (int u = 0; u < 8; ++u) {
      const int nn = 8 * k + u;
      const int nr = (nn + r) & 63;
      const float p0 = A_[r * 256 + 0 * 64 + nr];
      const float p1 = A_[r * 256 + 1 * 64 + nr];
      const float p2 = A_[r * 256 + 2 * 64 + nr];
      const float p3 = A_[r * 256 + 3 * 64 + nr];
      float s = (p0 + p1) + (p2 + p3);  // numpy pairwise combine
      float mean = s / 32.0f;           // exact (pow2)
      float sg = sigma[nn];
      float den = 2.0f * sg * sg;
      float dist = expf((-mean) / den);
      A_[r * 256 + nr] = dist;          // swizzled dist store
      if (dist < best) { best = dist; bi = nn; }  // local first-min
    }
#pragma unroll
    for (int m = 1; m < 8; m <<= 1) {
      const float ob = __shfl_xor(best, m);
      const int obi = __shfl_xor(bi, m);
      if (ob < best || (ob == best && obi < bi)) { best = ob; bi = obi; }
    }
    if (k == 0) {
      const size_t row = (size_t)blockRow + r;
      idxArr[r] = (float)bi;
      out1[row] = best;
      out2[row] = (float)bi;
    }
  }
  __syncthreads();

  // ---- S7a: distance matrix out (undo swizzle) ----
  for (int i = t; i < 32 * 64; i += 256) {
    int r = i >> 6, n = i & 63;
    out4[(size_t)(blockRow + r) * 64 + n] = A_[r * 256 + ((n + r) & 63)];
  }
  // ---- S7b: chosen embedding (recompute f2e[idx]) + chosen mean ----
  for (int i = t; i < 32 * 32; i += 256) {
    int r = i >> 5, e = i & 31;
    int bi = (int)idxArr[r];
    const float* wrow = Wp + (bi * 32 + e) * 128;
    float acc = 0.f;
    for (int f4 = 0; f4 < 128; f4 += 4) {
      const float4 wv = *(const float4*)(wrow + f4);
      const float4 fv = *(const float4*)&Bb[r * 128 + f4];
      acc = fmaf(fv.x, wv.x, acc);
      acc = fmaf(fv.y, wv.y, acc);
      acc = fmaf(fv.z, wv.z, acc);
      acc = fmaf(fv.w, wv.w, acc);
    }
    size_t row = (size_t)blockRow + r;
    out0[row * 32 + e] = acc;
    out3[row * 32 + e] = emb[bi * 32 + e];
  }
}

extern "C" void kernel_launch(void* const* d_in, const int* in_sizes, int n_in,
                              void* d_out, int out_size, void* d_ws, size_t ws_size,
                              hipStream_t stream) {
  const float* obs   = (const float*)d_in[0];
  const float* act   = (const float*)d_in[1];
  const float* obs2  = (const float*)d_in[2];
  const float* rew   = (const float*)d_in[3];
  const float* W0    = (const float*)d_in[4];
  const float* b0    = (const float*)d_in[5];
  const float* W1    = (const float*)d_in[6];
  const float* b1    = (const float*)d_in[7];
  const float* W2    = (const float*)d_in[8];
  const float* b2    = (const float*)d_in[9];
  const float* Wp    = (const float*)d_in[10];
  const float* e_emb = (const float*)d_in[11];
  const float* sigma = (const float*)d_in[12];

  const bool coal = (d_ws != nullptr) && (ws_size >= WPT_FLOATS * sizeof(float));
  float* WpT = coal ? (float*)d_ws : nullptr;

  udp_mlp<<<dim3(B_TOT / 32), dim3(256), 0, stream>>>(
      obs, act, obs2, rew, W0, b0, W1, b1, W2, b2, Wp, WpT, (float*)d_out);
  if (coal) {
    udp_dist<1><<<dim3(B_TOT / 32), dim3(256), 0, stream>>>(
        Wp, WpT, e_emb, sigma, (float*)d_out);
  } else {
    udp_dist<0><<<dim3(B_TOT / 32), dim3(256), 0, stream>>>(
        Wp, Wp, e_emb, sigma, (float*)d_out);
  }
}

// Round 16
// 848.287 us; speedup vs baseline: 1.0939x; 1.0939x over previous
//
#include <hip/hip_runtime.h>
#include <hip/hip_bf16.h>

#define B_TOT 65536
#define WPT_FLOATS (64 * 32 * 128)  // 262144 floats = 1 MiB

// Round-16: R14 base (best: 910us; dist 625) with S5 re-tiled to
// 4 dims x 16 rows (q=2 batches of 16): WpT is re-read 2x per block
// instead of 4x -> L2->CU traffic 8.6 -> 4.3 GB, global loads halve.
// Live set ~120 floats: with launch_bounds(256,2) the allocator picks the
// ~128-VGPR tier (R2 precedent), and 128 VGPR still allows 4 waves/SIMD
// while LDS (49.3KB) caps at 3 blocks/CU -> occupancy unchanged.
// R15's readfirstlane + unroll-4 reverted (regressed).
// Bit-exact: per-chain rj update order (m=2mm then 2mm+1, ascending) and
// dot order (ff-ascending, xyzw) identical to baseline.

// ---------------- Kernel A: MLP (+ WpT staging prologue) ----------------
__global__ __launch_bounds__(256, 2) void udp_mlp(
    const float* __restrict__ obs, const float* __restrict__ act,
    const float* __restrict__ obs2, const float* __restrict__ rew,
    const float* __restrict__ W0, const float* __restrict__ b0,
    const float* __restrict__ W1, const float* __restrict__ b1,
    const float* __restrict__ W2, const float* __restrict__ b2,
    const float* __restrict__ Wp, float* __restrict__ WpT,
    float* __restrict__ out) {
  __shared__ __align__(16) float A_[5120];   // xs[32][160] 20KB
  __shared__ __align__(16) float Bb[8192];   // h1->h2 [32][256] 32KB
  const int t = threadIdx.x;
  const int blockRow = blockIdx.x * 32;

  float* out0 = out;                        // feat[:,0:32) stash
  float* out3 = out + (size_t)B_TOT * 34;   // feat[:,32:64) stash
  float* out4 = out + (size_t)B_TOT * 66;   // feat[:,64:128) stash

  // ---- S0: WpT staging slice (128 elems/block; 2048*128 = 262144) ----
  // WpT[idx], idx = e*8192 + f4*256 + n*4 + j <- Wp[(n*32+e)*128 + f4*4 + j]
  if (WpT != nullptr && t < 128) {
    const int idx = blockIdx.x * 128 + t;
    const int j  = idx & 3;
    const int n  = (idx >> 2) & 63;
    const int f4 = (idx >> 8) & 31;
    const int e  = idx >> 13;
    WpT[idx] = Wp[(n * 32 + e) * 128 + f4 * 4 + j];
  }

  // ---- S1: stage x = [obs | obs2-obs | act | rew] into A_ ----
  for (int i = t; i < 32 * 160; i += 256) {
    int r = i / 160, k = i - r * 160;
    int row = blockRow + r;
    float v;
    if (k < 64)        v = obs[row * 64 + k];
    else if (k < 128)  v = obs2[row * 64 + (k - 64)] - obs[row * 64 + (k - 64)];
    else if (k < 144)  v = act[row * 16 + (k - 128)];
    else if (k == 144) v = rew[row];
    else               v = 0.f;
    A_[i] = v;
  }
  __syncthreads();

  // ---- S2: layer 0 (145 -> 256). 4 neurons x 8 rows per thread ----
  {
    const int n4 = (t & 63) * 4;
    const int rbase = (t >> 6) * 8;  // wave-uniform
    float aA[8], aB[8], aC[8], aD[8];
#pragma unroll
    for (int r = 0; r < 8; ++r) { aA[r] = 0.f; aB[r] = 0.f; aC[r] = 0.f; aD[r] = 0.f; }
    const float4 bb = *(const float4*)&b0[n4];
    const float4 wt = *(const float4*)&W0[144 * 256 + n4];
    for (int k4 = 0; k4 < 144; k4 += 4) {
      const float4 w0 = *(const float4*)&W0[(k4 + 0) * 256 + n4];
      const float4 w1 = *(const float4*)&W0[(k4 + 1) * 256 + n4];
      const float4 w2 = *(const float4*)&W0[(k4 + 2) * 256 + n4];
      const float4 w3 = *(const float4*)&W0[(k4 + 3) * 256 + n4];
#pragma unroll
      for (int r = 0; r < 8; ++r) {
        const float4 xv = *(const float4*)&A_[(rbase + r) * 160 + k4];  // broadcast
        aA[r] = fmaf(xv.x, w0.x, aA[r]); aA[r] = fmaf(xv.y, w1.x, aA[r]);
        aA[r] = fmaf(xv.z, w2.x, aA[r]); aA[r] = fmaf(xv.w, w3.x, aA[r]);
        aB[r] = fmaf(xv.x, w0.y, aB[r]); aB[r] = fmaf(xv.y, w1.y, aB[r]);
        aB[r] = fmaf(xv.z, w2.y, aB[r]); aB[r] = fmaf(xv.w, w3.y, aB[r]);
        aC[r] = fmaf(xv.x, w0.z, aC[r]); aC[r] = fmaf(xv.y, w1.z, aC[r]);
        aC[r] = fmaf(xv.z, w2.z, aC[r]); aC[r] = fmaf(xv.w, w3.z, aC[r]);
        aD[r] = fmaf(xv.x, w0.w, aD[r]); aD[r] = fmaf(xv.y, w1.w, aD[r]);
        aD[r] = fmaf(xv.z, w2.w, aD[r]); aD[r] = fmaf(xv.w, w3.w, aD[r]);
      }
    }
#pragma unroll
    for (int r = 0; r < 8; ++r) {
      const float xt = A_[(rbase + r) * 160 + 144];
      aA[r] = fmaf(xt, wt.x, aA[r]); aB[r] = fmaf(xt, wt.y, aB[r]);
      aC[r] = fmaf(xt, wt.z, aC[r]); aD[r] = fmaf(xt, wt.w, aD[r]);
    }
#pragma unroll
    for (int r = 0; r < 8; ++r) {
      float4 v;
      v.x = aA[r] + bb.x; v.x = v.x > 0.f ? v.x : 0.01f * v.x;
      v.y = aB[r] + bb.y; v.y = v.y > 0.f ? v.y : 0.01f * v.y;
      v.z = aC[r] + bb.z; v.z = v.z > 0.f ? v.z : 0.01f * v.z;
      v.w = aD[r] + bb.w; v.w = v.w > 0.f ? v.w : 0.01f * v.w;
      *(float4*)&Bb[(rbase + r) * 256 + n4] = v;  // h1
    }
  }
  __syncthreads();

  // ---- S3: layer 1 (256 -> 256). h2 overwrites h1 (barrier before write) ----
  {
    const int n4 = (t & 63) * 4;
    const int rbase = (t >> 6) * 8;
    float aA[8], aB[8], aC[8], aD[8];
#pragma unroll
    for (int r = 0; r < 8; ++r) { aA[r] = 0.f; aB[r] = 0.f; aC[r] = 0.f; aD[r] = 0.f; }
    const float4 bb = *(const float4*)&b1[n4];
    for (int k4 = 0; k4 < 256; k4 += 4) {
      const float4 w0 = *(const float4*)&W1[(k4 + 0) * 256 + n4];
      const float4 w1 = *(const float4*)&W1[(k4 + 1) * 256 + n4];
      const float4 w2 = *(const float4*)&W1[(k4 + 2) * 256 + n4];
      const float4 w3 = *(const float4*)&W1[(k4 + 3) * 256 + n4];
#pragma unroll
      for (int r = 0; r < 8; ++r) {
        const float4 xv = *(const float4*)&Bb[(rbase + r) * 256 + k4];  // broadcast
        aA[r] = fmaf(xv.x, w0.x, aA[r]); aA[r] = fmaf(xv.y, w1.x, aA[r]);
        aA[r] = fmaf(xv.z, w2.x, aA[r]); aA[r] = fmaf(xv.w, w3.x, aA[r]);
        aB[r] = fmaf(xv.x, w0.y, aB[r]); aB[r] = fmaf(xv.y, w1.y, aB[r]);
        aB[r] = fmaf(xv.z, w2.y, aB[r]); aB[r] = fmaf(xv.w, w3.y, aB[r]);
        aC[r] = fmaf(xv.x, w0.z, aC[r]); aC[r] = fmaf(xv.y, w1.z, aC[r]);
        aC[r] = fmaf(xv.z, w2.z, aC[r]); aC[r] = fmaf(xv.w, w3.z, aC[r]);
        aD[r] = fmaf(xv.x, w0.w, aD[r]); aD[r] = fmaf(xv.y, w1.w, aD[r]);
        aD[r] = fmaf(xv.z, w2.w, aD[r]); aD[r] = fmaf(xv.w, w3.w, aD[r]);
      }
    }
    __syncthreads();  // all h1 reads done before any h2 write
#pragma unroll
    for (int r = 0; r < 8; ++r) {
      float4 v;
      v.x = aA[r] + bb.x; v.x = v.x > 0.f ? v.x : 0.01f * v.x;
      v.y = aB[r] + bb.y; v.y = v.y > 0.f ? v.y : 0.01f * v.y;
      v.z = aC[r] + bb.z; v.z = v.z > 0.f ? v.z : 0.01f * v.z;
      v.w = aD[r] + bb.w; v.w = v.w > 0.f ? v.w : 0.01f * v.w;
      *(float4*)&Bb[(rbase + r) * 256 + n4] = v;  // h2 (in place)
    }
  }
  __syncthreads();

  // ---- S4: layer 2 (256 -> 128). 4 neurons x 4 rows; feat -> global stash ----
  {
    const int n4 = (t & 31) * 4;
    const int rbase = (t >> 5) * 4;
    float aA[4], aB[4], aC[4], aD[4];
#pragma unroll
    for (int r = 0; r < 4; ++r) { aA[r] = 0.f; aB[r] = 0.f; aC[r] = 0.f; aD[r] = 0.f; }
    const float4 bb = *(const float4*)&b2[n4];
    for (int k4 = 0; k4 < 256; k4 += 4) {
      const float4 w0 = *(const float4*)&W2[(k4 + 0) * 128 + n4];
      const float4 w1 = *(const float4*)&W2[(k4 + 1) * 128 + n4];
      const float4 w2 = *(const float4*)&W2[(k4 + 2) * 128 + n4];
      const float4 w3 = *(const float4*)&W2[(k4 + 3) * 128 + n4];
#pragma unroll
      for (int r = 0; r < 4; ++r) {
        const float4 xv = *(const float4*)&Bb[(rbase + r) * 256 + k4];
        aA[r] = fmaf(xv.x, w0.x, aA[r]); aA[r] = fmaf(xv.y, w1.x, aA[r]);
        aA[r] = fmaf(xv.z, w2.x, aA[r]); aA[r] = fmaf(xv.w, w3.x, aA[r]);
        aB[r] = fmaf(xv.x, w0.y, aB[r]); aB[r] = fmaf(xv.y, w1.y, aB[r]);
        aB[r] = fmaf(xv.z, w2.y, aB[r]); aB[r] = fmaf(xv.w, w3.y, aB[r]);
        aC[r] = fmaf(xv.x, w0.z, aC[r]); aC[r] = fmaf(xv.y, w1.z, aC[r]);
        aC[r] = fmaf(xv.z, w2.z, aC[r]); aC[r] = fmaf(xv.w, w3.z, aC[r]);
        aD[r] = fmaf(xv.x, w0.w, aD[r]); aD[r] = fmaf(xv.y, w1.w, aD[r]);
        aD[r] = fmaf(xv.z, w2.w, aD[r]); aD[r] = fmaf(xv.w, w3.w, aD[r]);
      }
    }
#pragma unroll
    for (int r = 0; r < 4; ++r) {
      float4 v;
      v.x = aA[r] + bb.x; v.x = v.x > 0.f ? v.x : 0.01f * v.x;
      v.y = aB[r] + bb.y; v.y = v.y > 0.f ? v.y : 0.01f * v.y;
      v.z = aC[r] + bb.z; v.z = v.z > 0.f ? v.z : 0.01f * v.z;
      v.w = aD[r] + bb.w; v.w = v.w > 0.f ? v.w : 0.01f * v.w;
      const size_t row = (size_t)blockRow + rbase + r;
      if (n4 < 32)      *(float4*)&out0[row * 32 + n4] = v;
      else if (n4 < 64) *(float4*)&out3[row * 32 + (n4 - 32)] = v;
      else              *(float4*)&out4[row * 64 + (n4 - 64)] = v;
    }
  }
}

// ---------------- Kernel B: projection + distance + outputs ----------------
// COAL=1: Wp loads from WpT (coalesced, lane-stride 16B).
// COAL=0: fallback direct-Wp when ws too small.
template <int COAL>
__global__ __launch_bounds__(256, 2) void udp_dist(
    const float* __restrict__ Wp, const float* __restrict__ WpT,
    const float* __restrict__ emb, const float* __restrict__ sigma,
    float* __restrict__ out) {
  __shared__ __align__(16) float A_[8192];   // psum[32][4][64] swizzled, 32KB
  __shared__ __align__(16) float Bb[4096];   // feat[32][128] 16KB
  __shared__ float idxArr[32];
  const int t = threadIdx.x;
  const int blockRow = blockIdx.x * 32;

  float* out0 = out;                        // chosen_embedding (B,32) [feat stash 0:32]
  float* out1 = out + (size_t)B_TOT * 32;   // chosen_dist (B,1)
  float* out2 = out + (size_t)B_TOT * 33;   // idx (B,1) as float
  float* out3 = out + (size_t)B_TOT * 34;   // chosen_mean (B,32) [feat stash 32:64]
  float* out4 = out + (size_t)B_TOT * 66;   // distance (B,64)  [feat stash 64:128]

  // ---- F1: load feat stash -> LDS ----
  for (int i = t; i < 1024; i += 256) {   // 1024 float4s = 32*128
    const int r = i >> 5, c4 = (i & 31) * 4;
    const size_t row = (size_t)blockRow + r;
    float4 v;
    if (c4 < 32)      v = *(const float4*)&out0[row * 32 + c4];
    else if (c4 < 64) v = *(const float4*)&out3[row * 32 + (c4 - 32)];
    else              v = *(const float4*)&out4[row * 64 + (c4 - 64)];
    *(float4*)&Bb[r * 128 + c4] = v;
  }
  __syncthreads();

  // ---- S5: projection + diff^2, 4 emb-dims x 16 rows per pass ----
  // thread = (env n = t&63, partial pp = t>>6). Owns numpy chains j=2p,2p+1.
  // Per mm: e00=2pp+16mm (m=2mm), e01=e00+1, e10=e00+8 (m=2mm+1), e11=e00+9.
  // q=2 batches of 16 rows -> WpT read 2x per block (was 4x).
  // rj updates m-ascending; dots ff-ascending xyzw -> bit-exact.
  {
    const int n = t & 63, pp = t >> 6;
    const float* eb = emb + n * 32;
#pragma unroll 1
    for (int q = 0; q < 2; ++q) {
      const int rbase = q * 16;
      float rj0[16], rj1[16];
#pragma unroll
      for (int r = 0; r < 16; ++r) { rj0[r] = 0.f; rj1[r] = 0.f; }
#pragma unroll 1
      for (int mm = 0; mm < 2; ++mm) {
        const int e00 = 2 * pp + 16 * mm;  // m = 2mm
        const int e01 = e00 + 1;
        const int e10 = e00 + 8;           // m = 2mm+1
        const int e11 = e00 + 9;
        const float *p00, *p01, *p10, *p11;
        if (COAL) {
          p00 = WpT + e00 * 8192 + n * 4;
          p01 = WpT + e01 * 8192 + n * 4;
          p10 = WpT + e10 * 8192 + n * 4;
          p11 = WpT + e11 * 8192 + n * 4;
        } else {
          p00 = Wp + ((size_t)n * 32 + e00) * 128;
          p01 = Wp + ((size_t)n * 32 + e01) * 128;
          p10 = Wp + ((size_t)n * 32 + e10) * 128;
          p11 = Wp + ((size_t)n * 32 + e11) * 128;
        }
        const int WSTR = COAL ? 256 : 4;
        float a00[16], a01[16], a10[16], a11[16];
#pragma unroll
        for (int r = 0; r < 16; ++r) { a00[r] = 0.f; a01[r] = 0.f; a10[r] = 0.f; a11[r] = 0.f; }
        for (int ff = 0; ff < 32; ++ff) {
          const float4 w00 = *(const float4*)(p00 + ff * WSTR);
          const float4 w01 = *(const float4*)(p01 + ff * WSTR);
          const float4 w10 = *(const float4*)(p10 + ff * WSTR);
          const float4 w11 = *(const float4*)(p11 + ff * WSTR);
#pragma unroll
          for (int r = 0; r < 16; ++r) {
            const float4 fv = *(const float4*)&Bb[(rbase + r) * 128 + ff * 4];  // broadcast
            a00[r] = fmaf(fv.x, w00.x, a00[r]);
            a00[r] = fmaf(fv.y, w00.y, a00[r]);
            a00[r] = fmaf(fv.z, w00.z, a00[r]);
            a00[r] = fmaf(fv.w, w00.w, a00[r]);
            a01[r] = fmaf(fv.x, w01.x, a01[r]);
            a01[r] = fmaf(fv.y, w01.y, a01[r]);
            a01[r] = fmaf(fv.z, w01.z, a01[r]);
            a01[r] = fmaf(fv.w, w01.w, a01[r]);
            a10[r] = fmaf(fv.x, w10.x, a10[r]);
            a10[r] = fmaf(fv.y, w10.y, a10[r]);
            a10[r] = fmaf(fv.z, w10.z, a10[r]);
            a10[r] = fmaf(fv.w, w10.w, a10[r]);
            a11[r] = fmaf(fv.x, w11.x, a11[r]);
            a11[r] = fmaf(fv.y, w11.y, a11[r]);
            a11[r] = fmaf(fv.z, w11.z, a11[r]);
            a11[r] = fmaf(fv.w, w11.w, a11[r]);
          }
        }
        const float em00 = eb[e00], em01 = eb[e01];
        const float em10 = eb[e10], em11 = eb[e11];
#pragma unroll
        for (int r = 0; r < 16; ++r) {
          // m-ascending per chain: m=2mm first, then m=2mm+1
          float d;
          d = a00[r] - em00; rj0[r] = fmaf(d, d, rj0[r]);
          d = a01[r] - em01; rj1[r] = fmaf(d, d, rj1[r]);
          d = a10[r] - em10; rj0[r] = fmaf(d, d, rj0[r]);
          d = a11[r] - em11; rj1[r] = fmaf(d, d, rj1[r]);
        }
      }
      // psum[r][pp][(n+gr)&63]: write 2-way (free), S6 read conflict-free
#pragma unroll
      for (int r = 0; r < 16; ++r) {
        const int gr = rbase + r;
        A_[gr * 256 + pp * 64 + ((n + gr) & 63)] = rj0[r] + rj1[r];
      }
    }
  }
  __syncthreads();

  // ---- S6: distance + argmin, parallel: thread (r = t>>3, k = t&7) ----
  // covers nn in [8k, 8k+8) ascending (thread-local first-min), then
  // 3-step shfl_xor (val,idx) reduce with smaller-index tie-break ==
  // np.argmin first-min exactly. dist values bit-identical.
  {
    const int r = t >> 3, k = t & 7;
    float best = 1e30f;
    int bi = 0;
    for (int u = 0; u < 8; ++u) {
      const int nn = 8 * k + u;
      const int nr = (nn + r) & 63;
      const float p0 = A_[r * 256 + 0 * 64 + nr];
      const float p1 = A_[r * 256 + 1 * 64 + nr];
      const float p2 = A_[r * 256 + 2 * 64 + nr];
      const float p3 = A_[r * 256 + 3 * 64 + nr];
      float s = (p0 + p1) + (p2 + p3);  // numpy pairwise combine
      float mean = s / 32.0f;           // exact (pow2)
      float sg = sigma[nn];
      float den = 2.0f * sg * sg;
      float dist = expf((-mean) / den);
      A_[r * 256 + nr] = dist;          // swizzled dist store
      if (dist < best) { best = dist; bi = nn; }  // local first-min
    }
#pragma unroll
    for (int m = 1; m < 8; m <<= 1) {
      const float ob = __shfl_xor(best, m);
      const int obi = __shfl_xor(bi, m);
      if (ob < best || (ob == best && obi < bi)) { best = ob; bi = obi; }
    }
    if (k == 0) {
      const size_t row = (size_t)blockRow + r;
      idxArr[r] = (float)bi;
      out1[row] = best;
      out2[row] = (float)bi;
    }
  }
  __syncthreads();

  // ---- S7a: distance matrix out (undo swizzle) ----
  for (int i = t; i < 32 * 64; i += 256) {
    int r = i >> 6, n = i & 63;
    out4[(size_t)(blockRow + r) * 64 + n] = A_[r * 256 + ((n + r) & 63)];
  }
  // ---- S7b: chosen embedding (recompute f2e[idx]) + chosen mean ----
  for (int i = t; i < 32 * 32; i += 256) {
    int r = i >> 5, e = i & 31;
    int bi = (int)idxArr[r];
    const float* wrow = Wp + (bi * 32 + e) * 128;
    float acc = 0.f;
    for (int f4 = 0; f4 < 128; f4 += 4) {
      const float4 wv = *(const float4*)(wrow + f4);
      const float4 fv = *(const float4*)&Bb[r * 128 + f4];
      acc = fmaf(fv.x, wv.x, acc);
      acc = fmaf(fv.y, wv.y, acc);
      acc = fmaf(fv.z, wv.z, acc);
      acc = fmaf(fv.w, wv.w, acc);
    }
    size_t row = (size_t)blockRow + r;
    out0[row * 32 + e] = acc;
    out3[row * 32 + e] = emb[bi * 32 + e];
  }
}

extern "C" void kernel_launch(void* const* d_in, const int* in_sizes, int n_in,
                              void* d_out, int out_size, void* d_ws, size_t ws_size,
                              hipStream_t stream) {
  const float* obs   = (const float*)d_in[0];
  const float* act   = (const float*)d_in[1];
  const float* obs2  = (const float*)d_in[2];
  const float* rew   = (const float*)d_in[3];
  const float* W0    = (const float*)d_in[4];
  const float* b0    = (const float*)d_in[5];
  const float* W1    = (const float*)d_in[6];
  const float* b1    = (const float*)d_in[7];
  const float* W2    = (const float*)d_in[8];
  const float* b2    = (const float*)d_in[9];
  const float* Wp    = (const float*)d_in[10];
  const float* e_emb = (const float*)d_in[11];
  const float* sigma = (const float*)d_in[12];

  const bool coal = (d_ws != nullptr) && (ws_size >= WPT_FLOATS * sizeof(float));
  float* WpT = coal ? (float*)d_ws : nullptr;

  udp_mlp<<<dim3(B_TOT / 32), dim3(256), 0, stream>>>(
      obs, act, obs2, rew, W0, b0, W1, b1, W2, b2, Wp, WpT, (float*)d_out);
  if (coal) {
    udp_dist<1><<<dim3(B_TOT / 32), dim3(256), 0, stream>>>(
        Wp, WpT, e_emb, sigma, (float*)d_out);
  } else {
    udp_dist<0><<<dim3(B_TOT / 32), dim3(256), 0, stream>>>(
        Wp, Wp, e_emb, sigma, (float*)d_out);
  }
}

// Round 17
// 823.608 us; speedup vs baseline: 1.1266x; 1.0300x over previous
//
#include <hip/hip_runtime.h>
#include <hip/hip_bf16.h>

#define B_TOT 65536
#define WPT_FLOATS (64 * 32 * 128)  // 262144 floats = 1 MiB

// Round-17: R16 + udp_dist fully batched over 16-row halves so LDS drops
// 49.6KB -> 24.6KB (feat batch 8K + psum 16K + idx) -> 6 blocks/CU (was 3).
// R16 evidence: VGPR count follows code need (84), NOT the LDS budget, so
// the same S5 code keeps its 84-VGPR codegen; 84 admits exactly 6 waves/SIMD.
// Per batch: F1(feat rows)->S5(R16 tiling, unchanged)->S6(parallel shuffle
// argmin, 128 thr)->S7a/S7b for those rows. WpT L2 traffic unchanged (q=2).
// Bit-exact: S5/S6 arithmetic + order byte-identical to R16.
// Tripwire: VGPR 64 + WRITE_SIZE spike = spill -> revert.

// ---------------- Kernel A: MLP (+ WpT staging prologue) ----------------
__global__ __launch_bounds__(256, 2) void udp_mlp(
    const float* __restrict__ obs, const float* __restrict__ act,
    const float* __restrict__ obs2, const float* __restrict__ rew,
    const float* __restrict__ W0, const float* __restrict__ b0,
    const float* __restrict__ W1, const float* __restrict__ b1,
    const float* __restrict__ W2, const float* __restrict__ b2,
    const float* __restrict__ Wp, float* __restrict__ WpT,
    float* __restrict__ out) {
  __shared__ __align__(16) float A_[5120];   // xs[32][160] 20KB
  __shared__ __align__(16) float Bb[8192];   // h1->h2 [32][256] 32KB
  const int t = threadIdx.x;
  const int blockRow = blockIdx.x * 32;

  float* out0 = out;                        // feat[:,0:32) stash
  float* out3 = out + (size_t)B_TOT * 34;   // feat[:,32:64) stash
  float* out4 = out + (size_t)B_TOT * 66;   // feat[:,64:128) stash

  // ---- S0: WpT staging slice (128 elems/block; 2048*128 = 262144) ----
  // WpT[idx], idx = e*8192 + f4*256 + n*4 + j <- Wp[(n*32+e)*128 + f4*4 + j]
  if (WpT != nullptr && t < 128) {
    const int idx = blockIdx.x * 128 + t;
    const int j  = idx & 3;
    const int n  = (idx >> 2) & 63;
    const int f4 = (idx >> 8) & 31;
    const int e  = idx >> 13;
    WpT[idx] = Wp[(n * 32 + e) * 128 + f4 * 4 + j];
  }

  // ---- S1: stage x = [obs | obs2-obs | act | rew] into A_ ----
  for (int i = t; i < 32 * 160; i += 256) {
    int r = i / 160, k = i - r * 160;
    int row = blockRow + r;
    float v;
    if (k < 64)        v = obs[row * 64 + k];
    else if (k < 128)  v = obs2[row * 64 + (k - 64)] - obs[row * 64 + (k - 64)];
    else if (k < 144)  v = act[row * 16 + (k - 128)];
    else if (k == 144) v = rew[row];
    else               v = 0.f;
    A_[i] = v;
  }
  __syncthreads();

  // ---- S2: layer 0 (145 -> 256). 4 neurons x 8 rows per thread ----
  {
    const int n4 = (t & 63) * 4;
    const int rbase = (t >> 6) * 8;  // wave-uniform
    float aA[8], aB[8], aC[8], aD[8];
#pragma unroll
    for (int r = 0; r < 8; ++r) { aA[r] = 0.f; aB[r] = 0.f; aC[r] = 0.f; aD[r] = 0.f; }
    const float4 bb = *(const float4*)&b0[n4];
    const float4 wt = *(const float4*)&W0[144 * 256 + n4];
    for (int k4 = 0; k4 < 144; k4 += 4) {
      const float4 w0 = *(const float4*)&W0[(k4 + 0) * 256 + n4];
      const float4 w1 = *(const float4*)&W0[(k4 + 1) * 256 + n4];
      const float4 w2 = *(const float4*)&W0[(k4 + 2) * 256 + n4];
      const float4 w3 = *(const float4*)&W0[(k4 + 3) * 256 + n4];
#pragma unroll
      for (int r = 0; r < 8; ++r) {
        const float4 xv = *(const float4*)&A_[(rbase + r) * 160 + k4];  // broadcast
        aA[r] = fmaf(xv.x, w0.x, aA[r]); aA[r] = fmaf(xv.y, w1.x, aA[r]);
        aA[r] = fmaf(xv.z, w2.x, aA[r]); aA[r] = fmaf(xv.w, w3.x, aA[r]);
        aB[r] = fmaf(xv.x, w0.y, aB[r]); aB[r] = fmaf(xv.y, w1.y, aB[r]);
        aB[r] = fmaf(xv.z, w2.y, aB[r]); aB[r] = fmaf(xv.w, w3.y, aB[r]);
        aC[r] = fmaf(xv.x, w0.z, aC[r]); aC[r] = fmaf(xv.y, w1.z, aC[r]);
        aC[r] = fmaf(xv.z, w2.z, aC[r]); aC[r] = fmaf(xv.w, w3.z, aC[r]);
        aD[r] = fmaf(xv.x, w0.w, aD[r]); aD[r] = fmaf(xv.y, w1.w, aD[r]);
        aD[r] = fmaf(xv.z, w2.w, aD[r]); aD[r] = fmaf(xv.w, w3.w, aD[r]);
      }
    }
#pragma unroll
    for (int r = 0; r < 8; ++r) {
      const float xt = A_[(rbase + r) * 160 + 144];
      aA[r] = fmaf(xt, wt.x, aA[r]); aB[r] = fmaf(xt, wt.y, aB[r]);
      aC[r] = fmaf(xt, wt.z, aC[r]); aD[r] = fmaf(xt, wt.w, aD[r]);
    }
#pragma unroll
    for (int r = 0; r < 8; ++r) {
      float4 v;
      v.x = aA[r] + bb.x; v.x = v.x > 0.f ? v.x : 0.01f * v.x;
      v.y = aB[r] + bb.y; v.y = v.y > 0.f ? v.y : 0.01f * v.y;
      v.z = aC[r] + bb.z; v.z = v.z > 0.f ? v.z : 0.01f * v.z;
      v.w = aD[r] + bb.w; v.w = v.w > 0.f ? v.w : 0.01f * v.w;
      *(float4*)&Bb[(rbase + r) * 256 + n4] = v;  // h1
    }
  }
  __syncthreads();

  // ---- S3: layer 1 (256 -> 256). h2 overwrites h1 (barrier before write) ----
  {
    const int n4 = (t & 63) * 4;
    const int rbase = (t >> 6) * 8;
    float aA[8], aB[8], aC[8], aD[8];
#pragma unroll
    for (int r = 0; r < 8; ++r) { aA[r] = 0.f; aB[r] = 0.f; aC[r] = 0.f; aD[r] = 0.f; }
    const float4 bb = *(const float4*)&b1[n4];
    for (int k4 = 0; k4 < 256; k4 += 4) {
      const float4 w0 = *(const float4*)&W1[(k4 + 0) * 256 + n4];
      const float4 w1 = *(const float4*)&W1[(k4 + 1) * 256 + n4];
      const float4 w2 = *(const float4*)&W1[(k4 + 2) * 256 + n4];
      const float4 w3 = *(const float4*)&W1[(k4 + 3) * 256 + n4];
#pragma unroll
      for (int r = 0; r < 8; ++r) {
        const float4 xv = *(const float4*)&Bb[(rbase + r) * 256 + k4];  // broadcast
        aA[r] = fmaf(xv.x, w0.x, aA[r]); aA[r] = fmaf(xv.y, w1.x, aA[r]);
        aA[r] = fmaf(xv.z, w2.x, aA[r]); aA[r] = fmaf(xv.w, w3.x, aA[r]);
        aB[r] = fmaf(xv.x, w0.y, aB[r]); aB[r] = fmaf(xv.y, w1.y, aB[r]);
        aB[r] = fmaf(xv.z, w2.y, aB[r]); aB[r] = fmaf(xv.w, w3.y, aB[r]);
        aC[r] = fmaf(xv.x, w0.z, aC[r]); aC[r] = fmaf(xv.y, w1.z, aC[r]);
        aC[r] = fmaf(xv.z, w2.z, aC[r]); aC[r] = fmaf(xv.w, w3.z, aC[r]);
        aD[r] = fmaf(xv.x, w0.w, aD[r]); aD[r] = fmaf(xv.y, w1.w, aD[r]);
        aD[r] = fmaf(xv.z, w2.w, aD[r]); aD[r] = fmaf(xv.w, w3.w, aD[r]);
      }
    }
    __syncthreads();  // all h1 reads done before any h2 write
#pragma unroll
    for (int r = 0; r < 8; ++r) {
      float4 v;
      v.x = aA[r] + bb.x; v.x = v.x > 0.f ? v.x : 0.01f * v.x;
      v.y = aB[r] + bb.y; v.y = v.y > 0.f ? v.y : 0.01f * v.y;
      v.z = aC[r] + bb.z; v.z = v.z > 0.f ? v.z : 0.01f * v.z;
      v.w = aD[r] + bb.w; v.w = v.w > 0.f ? v.w : 0.01f * v.w;
      *(float4*)&Bb[(rbase + r) * 256 + n4] = v;  // h2 (in place)
    }
  }
  __syncthreads();

  // ---- S4: layer 2 (256 -> 128). 4 neurons x 4 rows; feat -> global stash ----
  {
    const int n4 = (t & 31) * 4;
    const int rbase = (t >> 5) * 4;
    float aA[4], aB[4], aC[4], aD[4];
#pragma unroll
    for (int r = 0; r < 4; ++r) { aA[r] = 0.f; aB[r] = 0.f; aC[r] = 0.f; aD[r] = 0.f; }
    const float4 bb = *(const float4*)&b2[n4];
    for (int k4 = 0; k4 < 256; k4 += 4) {
      const float4 w0 = *(const float4*)&W2[(k4 + 0) * 128 + n4];
      const float4 w1 = *(const float4*)&W2[(k4 + 1) * 128 + n4];
      const float4 w2 = *(const float4*)&W2[(k4 + 2) * 128 + n4];
      const float4 w3 = *(const float4*)&W2[(k4 + 3) * 128 + n4];
#pragma unroll
      for (int r = 0; r < 4; ++r) {
        const float4 xv = *(const float4*)&Bb[(rbase + r) * 256 + k4];
        aA[r] = fmaf(xv.x, w0.x, aA[r]); aA[r] = fmaf(xv.y, w1.x, aA[r]);
        aA[r] = fmaf(xv.z, w2.x, aA[r]); aA[r] = fmaf(xv.w, w3.x, aA[r]);
        aB[r] = fmaf(xv.x, w0.y, aB[r]); aB[r] = fmaf(xv.y, w1.y, aB[r]);
        aB[r] = fmaf(xv.z, w2.y, aB[r]); aB[r] = fmaf(xv.w, w3.y, aB[r]);
        aC[r] = fmaf(xv.x, w0.z, aC[r]); aC[r] = fmaf(xv.y, w1.z, aC[r]);
        aC[r] = fmaf(xv.z, w2.z, aC[r]); aC[r] = fmaf(xv.w, w3.z, aC[r]);
        aD[r] = fmaf(xv.x, w0.w, aD[r]); aD[r] = fmaf(xv.y, w1.w, aD[r]);
        aD[r] = fmaf(xv.z, w2.w, aD[r]); aD[r] = fmaf(xv.w, w3.w, aD[r]);
      }
    }
#pragma unroll
    for (int r = 0; r < 4; ++r) {
      float4 v;
      v.x = aA[r] + bb.x; v.x = v.x > 0.f ? v.x : 0.01f * v.x;
      v.y = aB[r] + bb.y; v.y = v.y > 0.f ? v.y : 0.01f * v.y;
      v.z = aC[r] + bb.z; v.z = v.z > 0.f ? v.z : 0.01f * v.z;
      v.w = aD[r] + bb.w; v.w = v.w > 0.f ? v.w : 0.01f * v.w;
      const size_t row = (size_t)blockRow + rbase + r;
      if (n4 < 32)      *(float4*)&out0[row * 32 + n4] = v;
      else if (n4 < 64) *(float4*)&out3[row * 32 + (n4 - 32)] = v;
      else              *(float4*)&out4[row * 64 + (n4 - 64)] = v;
    }
  }
}

// ---------------- Kernel B: projection + distance + outputs ----------------
// Fully batched over 16-row halves. COAL=1: coalesced WpT; COAL=0: fallback.
template <int COAL>
__global__ __launch_bounds__(256, 2) void udp_dist(
    const float* __restrict__ Wp, const float* __restrict__ WpT,
    const float* __restrict__ emb, const float* __restrict__ sigma,
    float* __restrict__ out) {
  __shared__ __align__(16) float Fb[2048];   // feat batch [16][128] 8KB
  __shared__ __align__(16) float P_[4096];   // psum batch [16][4][64] 16KB
  __shared__ float idxArr[16];
  const int t = threadIdx.x;
  const int blockRow = blockIdx.x * 32;

  float* out0 = out;                        // chosen_embedding (B,32) [feat stash 0:32]
  float* out1 = out + (size_t)B_TOT * 32;   // chosen_dist (B,1)
  float* out2 = out + (size_t)B_TOT * 33;   // idx (B,1) as float
  float* out3 = out + (size_t)B_TOT * 34;   // chosen_mean (B,32) [feat stash 32:64]
  float* out4 = out + (size_t)B_TOT * 66;   // distance (B,64)  [feat stash 64:128]

  const int n = t & 63, pp = t >> 6;
  const float* eb = emb + n * 32;

#pragma unroll 1
  for (int q = 0; q < 2; ++q) {
    const int rbase = q * 16;

    // ---- F1: load feat stash rows [rbase, rbase+16) -> Fb ----
    // (batch q reads rows this kernel has NOT yet overwritten: S7 of batch
    //  q-1 touched only rows < rbase.)
    for (int i = t; i < 512; i += 256) {   // 512 float4s = 16*128
      const int r = i >> 5, c4 = (i & 31) * 4;
      const size_t row = (size_t)blockRow + rbase + r;
      float4 v;
      if (c4 < 32)      v = *(const float4*)&out0[row * 32 + c4];
      else if (c4 < 64) v = *(const float4*)&out3[row * 32 + (c4 - 32)];
      else              v = *(const float4*)&out4[row * 64 + (c4 - 64)];
      *(float4*)&Fb[r * 128 + c4] = v;
    }
    __syncthreads();

    // ---- S5: projection + diff^2, 4 emb-dims x 16 rows (R16 tiling) ----
    // Per mm: e00=2pp+16mm (m=2mm), e01=e00+1, e10=e00+8 (m=2mm+1), e11=e00+9.
    // rj updates m-ascending; dots ff-ascending xyzw -> bit-exact.
    {
      float rj0[16], rj1[16];
#pragma unroll
      for (int r = 0; r < 16; ++r) { rj0[r] = 0.f; rj1[r] = 0.f; }
#pragma unroll 1
      for (int mm = 0; mm < 2; ++mm) {
        const int e00 = 2 * pp + 16 * mm;  // m = 2mm
        const int e01 = e00 + 1;
        const int e10 = e00 + 8;           // m = 2mm+1
        const int e11 = e00 + 9;
        const float *p00, *p01, *p10, *p11;
        if (COAL) {
          p00 = WpT + e00 * 8192 + n * 4;
          p01 = WpT + e01 * 8192 + n * 4;
          p10 = WpT + e10 * 8192 + n * 4;
          p11 = WpT + e11 * 8192 + n * 4;
        } else {
          p00 = Wp + ((size_t)n * 32 + e00) * 128;
          p01 = Wp + ((size_t)n * 32 + e01) * 128;
          p10 = Wp + ((size_t)n * 32 + e10) * 128;
          p11 = Wp + ((size_t)n * 32 + e11) * 128;
        }
        const int WSTR = COAL ? 256 : 4;
        float a00[16], a01[16], a10[16], a11[16];
#pragma unroll
        for (int r = 0; r < 16; ++r) { a00[r] = 0.f; a01[r] = 0.f; a10[r] = 0.f; a11[r] = 0.f; }
        for (int ff = 0; ff < 32; ++ff) {
          const float4 w00 = *(const float4*)(p00 + ff * WSTR);
          const float4 w01 = *(const float4*)(p01 + ff * WSTR);
          const float4 w10 = *(const float4*)(p10 + ff * WSTR);
          const float4 w11 = *(const float4*)(p11 + ff * WSTR);
#pragma unroll
          for (int r = 0; r < 16; ++r) {
            const float4 fv = *(const float4*)&Fb[r * 128 + ff * 4];  // broadcast
            a00[r] = fmaf(fv.x, w00.x, a00[r]);
            a00[r] = fmaf(fv.y, w00.y, a00[r]);
            a00[r] = fmaf(fv.z, w00.z, a00[r]);
            a00[r] = fmaf(fv.w, w00.w, a00[r]);
            a01[r] = fmaf(fv.x, w01.x, a01[r]);
            a01[r] = fmaf(fv.y, w01.y, a01[r]);
            a01[r] = fmaf(fv.z, w01.z, a01[r]);
            a01[r] = fmaf(fv.w, w01.w, a01[r]);
            a10[r] = fmaf(fv.x, w10.x, a10[r]);
            a10[r] = fmaf(fv.y, w10.y, a10[r]);
            a10[r] = fmaf(fv.z, w10.z, a10[r]);
            a10[r] = fmaf(fv.w, w10.w, a10[r]);
            a11[r] = fmaf(fv.x, w11.x, a11[r]);
            a11[r] = fmaf(fv.y, w11.y, a11[r]);
            a11[r] = fmaf(fv.z, w11.z, a11[r]);
            a11[r] = fmaf(fv.w, w11.w, a11[r]);
          }
        }
        const float em00 = eb[e00], em01 = eb[e01];
        const float em10 = eb[e10], em11 = eb[e11];
#pragma unroll
        for (int r = 0; r < 16; ++r) {
          // m-ascending per chain: m=2mm first, then m=2mm+1
          float d;
          d = a00[r] - em00; rj0[r] = fmaf(d, d, rj0[r]);
          d = a01[r] - em01; rj1[r] = fmaf(d, d, rj1[r]);
          d = a10[r] - em10; rj0[r] = fmaf(d, d, rj0[r]);
          d = a11[r] - em11; rj1[r] = fmaf(d, d, rj1[r]);
        }
      }
      // psum P_[r][pp][(n+gr)&63]: write 2-way (free), S6 read conflict-free
#pragma unroll
      for (int r = 0; r < 16; ++r) {
        const int gr = rbase + r;
        P_[r * 256 + pp * 64 + ((n + gr) & 63)] = rj0[r] + rj1[r];
      }
    }
    __syncthreads();

    // ---- S6: distance + argmin, parallel (t<128): r=t>>3, k=t&7 ----
    // nn in [8k,8k+8) ascending (local first-min), then 3-step shfl_xor
    // with smaller-index tie-break == np.argmin first-min exactly.
    if (t < 128) {
      const int r = t >> 3, k = t & 7;
      const int gr = rbase + r;
      float best = 1e30f;
      int bi = 0;
      for (int u = 0; u < 8; ++u) {
        const int nn = 8 * k + u;
        const int nr = (nn + gr) & 63;
        const float p0 = P_[r * 256 + 0 * 64 + nr];
        const float p1 = P_[r * 256 + 1 * 64 + nr];
        const float p2 = P_[r * 256 + 2 * 64 + nr];
        const float p3 = P_[r * 256 + 3 * 64 + nr];
        float s = (p0 + p1) + (p2 + p3);  // numpy pairwise combine
        float mean = s / 32.0f;           // exact (pow2)
        float sg = sigma[nn];
        float den = 2.0f * sg * sg;
        float dist = expf((-mean) / den);
        P_[r * 256 + nr] = dist;          // swizzled dist store
        if (dist < best) { best = dist; bi = nn; }  // local first-min
      }
#pragma unroll
      for (int m = 1; m < 8; m <<= 1) {
        const float ob = __shfl_xor(best, m);
        const int obi = __shfl_xor(bi, m);
        if (ob < best || (ob == best && obi < bi)) { best = ob; bi = obi; }
      }
      if (k == 0) {
        const size_t row = (size_t)blockRow + gr;
        idxArr[r] = (float)bi;
        out1[row] = best;
        out2[row] = (float)bi;
      }
    }
    __syncthreads();

    // ---- S7a: distance matrix out for batch (undo swizzle) ----
    for (int i = t; i < 1024; i += 256) {  // 16*64
      const int r = i >> 6, nn = i & 63;
      const int gr = rbase + r;
      out4[(size_t)(blockRow + gr) * 64 + nn] = P_[r * 256 + ((nn + gr) & 63)];
    }
    // ---- S7b: chosen embedding + chosen mean for batch ----
    for (int i = t; i < 512; i += 256) {   // 16*32
      const int r = i >> 5, e = i & 31;
      const int bi = (int)idxArr[r];
      const float* wrow = Wp + (bi * 32 + e) * 128;
      float acc = 0.f;
      for (int f4 = 0; f4 < 128; f4 += 4) {
        const float4 wv = *(const float4*)(wrow + f4);
        const float4 fv = *(const float4*)&Fb[r * 128 + f4];
        acc = fmaf(fv.x, wv.x, acc);
        acc = fmaf(fv.y, wv.y, acc);
        acc = fmaf(fv.z, wv.z, acc);
        acc = fmaf(fv.w, wv.w, acc);
      }
      const size_t row = (size_t)blockRow + rbase + r;
      out0[row * 32 + e] = acc;
      out3[row * 32 + e] = emb[bi * 32 + e];
    }
    __syncthreads();  // Fb/P_/idxArr reused by next batch
  }
}

extern "C" void kernel_launch(void* const* d_in, const int* in_sizes, int n_in,
                              void* d_out, int out_size, void* d_ws, size_t ws_size,
                              hipStream_t stream) {
  const float* obs   = (const float*)d_in[0];
  const float* act   = (const float*)d_in[1];
  const float* obs2  = (const float*)d_in[2];
  const float* rew   = (const float*)d_in[3];
  const float* W0    = (const float*)d_in[4];
  const float* b0    = (const float*)d_in[5];
  const float* W1    = (const float*)d_in[6];
  const float* b1    = (const float*)d_in[7];
  const float* W2    = (const float*)d_in[8];
  const float* b2    = (const float*)d_in[9];
  const float* Wp    = (const float*)d_in[10];
  const float* e_emb = (const float*)d_in[11];
  const float* sigma = (const float*)d_in[12];

  const bool coal = (d_ws != nullptr) && (ws_size >= WPT_FLOATS * sizeof(float));
  float* WpT = coal ? (float*)d_ws : nullptr;

  udp_mlp<<<dim3(B_TOT / 32), dim3(256), 0, stream>>>(
      obs, act, obs2, rew, W0, b0, W1, b1, W2, b2, Wp, WpT, (float*)d_out);
  if (coal) {
    udp_dist<1><<<dim3(B_TOT / 32), dim3(256), 0, stream>>>(
        Wp, WpT, e_emb, sigma, (float*)d_out);
  } else {
    udp_dist<0><<<dim3(B_TOT / 32), dim3(256), 0, stream>>>(
        Wp, Wp, e_emb, sigma, (float*)d_out);
  }
}